// Round 1
// baseline (244.041 us; speedup 1.0000x reference)
//
#include <hip/hip_runtime.h>
#include <hip/hip_bf16.h>
#include <cstdint>

#define B_ROWS 4096
#define DIM 1024
#define NN 8192  // 2*B

typedef __bf16 bf16x8 __attribute__((ext_vector_type(8)));
typedef __bf16 bf16x4 __attribute__((ext_vector_type(4)));
typedef float f32x4 __attribute__((ext_vector_type(4)));

__device__ __forceinline__ float wave_reduce_sum(float v) {
    v += __shfl_xor(v, 1);
    v += __shfl_xor(v, 2);
    v += __shfl_xor(v, 4);
    v += __shfl_xor(v, 8);
    v += __shfl_xor(v, 16);
    v += __shfl_xor(v, 32);
    return v;
}

__device__ __forceinline__ void gld_lds16(const void* g, void* l) {
    __builtin_amdgcn_global_load_lds(
        (__attribute__((address_space(1))) void*)(uintptr_t)g,
        (__attribute__((address_space(3))) void*)l, 16, 0, 0);
}

// Kernel 1: L2-normalize each row of proj_1 / proj_2 into bf16 rep [NN][DIM]
__global__ void normalize_kernel(const float* __restrict__ p1,
                                 const float* __restrict__ p2,
                                 __bf16* __restrict__ rep) {
    const int r = blockIdx.x;   // 0..8191
    const int t = threadIdx.x;  // 0..255, each handles one float4 (DIM=1024)
    const float* src = (r < B_ROWS) ? (p1 + (size_t)r * DIM)
                                    : (p2 + (size_t)(r - B_ROWS) * DIM);
    float4 v = ((const float4*)src)[t];
    float ss = v.x * v.x + v.y * v.y + v.z * v.z + v.w * v.w;
    ss = wave_reduce_sum(ss);
    __shared__ float red[4];
    const int lane = t & 63, wv = t >> 6;
    if (lane == 0) red[wv] = ss;
    __syncthreads();
    const float total = red[0] + red[1] + red[2] + red[3];
    const float sc = rsqrtf(total);
    bf16x4 o;
    o.x = (__bf16)(v.x * sc);
    o.y = (__bf16)(v.y * sc);
    o.z = (__bf16)(v.z * sc);
    o.w = (__bf16)(v.w * sc);
    *(bf16x4*)(rep + (size_t)r * DIM + t * 4) = o;
}

// Kernel 2: positives pos[i] = dot(rep[i], rep[i+B])
__global__ void pos_kernel(const __bf16* __restrict__ rep,
                           float* __restrict__ pos) {
    const int i = blockIdx.x;   // 0..4095
    const int t = threadIdx.x;  // 0..255
    bf16x4 a = *(const bf16x4*)(rep + (size_t)i * DIM + t * 4);
    bf16x4 b = *(const bf16x4*)(rep + (size_t)(i + B_ROWS) * DIM + t * 4);
    float s = (float)a.x * (float)b.x + (float)a.y * (float)b.y +
              (float)a.z * (float)b.z + (float)a.w * (float)b.w;
    s = wave_reduce_sum(s);
    __shared__ float red[4];
    const int lane = t & 63, wv = t >> 6;
    if (lane == 0) red[wv] = s;
    __syncthreads();
    if (t == 0) pos[i] = red[0] + red[1] + red[2] + red[3];
}

// Kernel 3: fused GEMM (sim tile) + exp + diag-mask + per-row partial sums.
// 128x128 tile per block, BK=32, 4 waves stacked vertically (32 rows each).
// partial[cb * NN + row] = sum over this tile's 128 cols of exp(2*sim) (diag masked)
__global__ __launch_bounds__(256) void gemm_kernel(const __bf16* __restrict__ rep,
                                                   float* __restrict__ partial) {
    __shared__ __bf16 As[128 * 32];
    __shared__ __bf16 Bs[128 * 32];
    const int t = threadIdx.x;
    const int lane = t & 63;
    const int wv = t >> 6;  // 0..3
    const int rb = blockIdx.y, cb = blockIdx.x;

    // staging: thread t loads row t>>2 (and +64), 16B segment t&3
    const __bf16* aS = rep + (size_t)(rb * 128 + (t >> 2)) * DIM + (t & 3) * 8;
    const __bf16* bS = rep + (size_t)(cb * 128 + (t >> 2)) * DIM + (t & 3) * 8;
    __bf16* aD = As + t * 8;  // byte offset t*16 (wave-uniform base + lane*16)
    __bf16* bD = Bs + t * 8;

    // fragment read bases: A[m=lane&15][k=(lane>>4)*8+j], same for B with n
    const __bf16* aF = As + (size_t)(wv * 32 + (lane & 15)) * 32 + ((lane >> 4) * 8);
    const __bf16* bF = Bs + (size_t)(lane & 15) * 32 + ((lane >> 4) * 8);

    f32x4 acc[2][8];
#pragma unroll
    for (int i = 0; i < 2; ++i)
#pragma unroll
        for (int j = 0; j < 8; ++j) acc[i][j] = (f32x4){0.f, 0.f, 0.f, 0.f};

    for (int kk = 0; kk < DIM / 32; ++kk) {
        const __bf16* a0 = aS + kk * 32;
        const __bf16* b0 = bS + kk * 32;
        gld_lds16(a0, aD);
        gld_lds16(a0 + 64 * DIM, aD + 2048);
        gld_lds16(b0, bD);
        gld_lds16(b0 + 64 * DIM, bD + 2048);
        __syncthreads();  // drains vmcnt (compiler-inserted) before LDS reads

        bf16x8 af[2], bfr[8];
#pragma unroll
        for (int mi = 0; mi < 2; ++mi) af[mi] = *(const bf16x8*)(aF + mi * 16 * 32);
#pragma unroll
        for (int ni = 0; ni < 8; ++ni) bfr[ni] = *(const bf16x8*)(bF + ni * 16 * 32);
#pragma unroll
        for (int mi = 0; mi < 2; ++mi)
#pragma unroll
            for (int ni = 0; ni < 8; ++ni)
                acc[mi][ni] = __builtin_amdgcn_mfma_f32_16x16x32_bf16(
                    af[mi], bfr[ni], acc[mi][ni], 0, 0, 0);
        __syncthreads();  // all reads done before next stage overwrites
    }

    // Epilogue: C/D layout col=lane&15, row=(lane>>4)*4+reg
    const int colbase = cb * 128 + (lane & 15);
#pragma unroll
    for (int mi = 0; mi < 2; ++mi) {
#pragma unroll
        for (int reg = 0; reg < 4; ++reg) {
            const int row_l = wv * 32 + mi * 16 + ((lane >> 4) << 2) + reg;
            const int grow = rb * 128 + row_l;
            float s = 0.f;
#pragma unroll
            for (int ni = 0; ni < 8; ++ni) {
                const int gcol = colbase + ni * 16;
                const float v = acc[mi][ni][reg];
                const float e = __expf(v * 2.0f);  // 1/T = 2
                s += (grow == gcol) ? 0.f : e;     // mask self-similarity
            }
            // reduce across the 16 lanes sharing this row
            s += __shfl_xor(s, 1);
            s += __shfl_xor(s, 2);
            s += __shfl_xor(s, 4);
            s += __shfl_xor(s, 8);
            if ((lane & 15) == 0) partial[(size_t)cb * NN + grow] = s;
        }
    }
}

// Kernel 4a: per-row denom -> per-row loss -> 32 block sums
__global__ void reduce_rows_kernel(const float* __restrict__ partial,
                                   const float* __restrict__ pos,
                                   float* __restrict__ bsum) {
    const int r = blockIdx.x * 256 + threadIdx.x;  // 32 blocks x 256 = 8192
    float s = 0.f;
    for (int kb = 0; kb < 64; ++kb) s += partial[(size_t)kb * NN + r];
    float v = __logf(s) - pos[r & (B_ROWS - 1)] * 2.0f;  // log(denom) - pos/T
    v = wave_reduce_sum(v);
    __shared__ float red[4];
    const int lane = threadIdx.x & 63, wv = threadIdx.x >> 6;
    if (lane == 0) red[wv] = v;
    __syncthreads();
    if (threadIdx.x == 0) bsum[blockIdx.x] = red[0] + red[1] + red[2] + red[3];
}

// Kernel 4b: final scalar
__global__ void final_kernel(const float* __restrict__ bsum,
                             float* __restrict__ out) {
    float s = (threadIdx.x < 32) ? bsum[threadIdx.x] : 0.f;
    s = wave_reduce_sum(s);
    if (threadIdx.x == 0) out[0] = s * (1.0f / NN);
}

extern "C" void kernel_launch(void* const* d_in, const int* in_sizes, int n_in,
                              void* d_out, int out_size, void* d_ws, size_t ws_size,
                              hipStream_t stream) {
    const float* p1 = (const float*)d_in[0];
    const float* p2 = (const float*)d_in[1];
    char* ws = (char*)d_ws;
    __bf16* rep = (__bf16*)ws;                                    // 16 MiB
    float* partial = (float*)(ws + (size_t)16 * 1024 * 1024);     // 2 MiB (64 x 8192)
    float* pos = (float*)(ws + (size_t)18 * 1024 * 1024);         // 16 KiB
    float* bsum = (float*)(ws + (size_t)18 * 1024 * 1024 + 16384);// 128 B
    float* out = (float*)d_out;

    normalize_kernel<<<NN, 256, 0, stream>>>(p1, p2, rep);
    pos_kernel<<<B_ROWS, 256, 0, stream>>>(rep, pos);
    gemm_kernel<<<dim3(64, 64), 256, 0, stream>>>(rep, partial);
    reduce_rows_kernel<<<32, 256, 0, stream>>>(partial, pos, bsum);
    final_kernel<<<1, 64, 0, stream>>>(bsum, out);
}

// Round 2
// 219.180 us; speedup vs baseline: 1.1134x; 1.1134x over previous
//
#include <hip/hip_runtime.h>
#include <hip/hip_bf16.h>
#include <cstdint>

#define B_ROWS 4096
#define DIM 1024
#define NN 8192  // 2*B

typedef __bf16 bf16x8 __attribute__((ext_vector_type(8)));
typedef __bf16 bf16x4 __attribute__((ext_vector_type(4)));
typedef float f32x4 __attribute__((ext_vector_type(4)));

__device__ __forceinline__ float wave_reduce_sum(float v) {
    v += __shfl_xor(v, 1);
    v += __shfl_xor(v, 2);
    v += __shfl_xor(v, 4);
    v += __shfl_xor(v, 8);
    v += __shfl_xor(v, 16);
    v += __shfl_xor(v, 32);
    return v;
}

__device__ __forceinline__ void gld_lds16(const void* g, void* l) {
    __builtin_amdgcn_global_load_lds(
        (__attribute__((address_space(1))) void*)(uintptr_t)g,
        (__attribute__((address_space(3))) void*)l, 16, 0, 0);
}

// Kernel 1: fused L2-normalize (both views) + fp32 positives.
// Block i handles row i of proj_1 and row i of proj_2.
__global__ void norm_pos_kernel(const float* __restrict__ p1,
                                const float* __restrict__ p2,
                                __bf16* __restrict__ rep,
                                float* __restrict__ pos) {
    const int i = blockIdx.x;   // 0..4095
    const int t = threadIdx.x;  // 0..255, one float4 each (DIM=1024)
    float4 a = ((const float4*)(p1 + (size_t)i * DIM))[t];
    float4 b = ((const float4*)(p2 + (size_t)i * DIM))[t];
    float s1 = a.x * a.x + a.y * a.y + a.z * a.z + a.w * a.w;
    float s2 = b.x * b.x + b.y * b.y + b.z * b.z + b.w * b.w;
    float dp = a.x * b.x + a.y * b.y + a.z * b.z + a.w * b.w;
    s1 = wave_reduce_sum(s1);
    s2 = wave_reduce_sum(s2);
    dp = wave_reduce_sum(dp);
    __shared__ float r1[4], r2[4], r3[4];
    const int lane = t & 63, wv = t >> 6;
    if (lane == 0) { r1[wv] = s1; r2[wv] = s2; r3[wv] = dp; }
    __syncthreads();
    const float t1 = r1[0] + r1[1] + r1[2] + r1[3];
    const float t2 = r2[0] + r2[1] + r2[2] + r2[3];
    const float td = r3[0] + r3[1] + r3[2] + r3[3];
    const float sc1 = rsqrtf(t1), sc2 = rsqrtf(t2);
    bf16x4 o1, o2;
    o1.x = (__bf16)(a.x * sc1); o1.y = (__bf16)(a.y * sc1);
    o1.z = (__bf16)(a.z * sc1); o1.w = (__bf16)(a.w * sc1);
    o2.x = (__bf16)(b.x * sc2); o2.y = (__bf16)(b.y * sc2);
    o2.z = (__bf16)(b.z * sc2); o2.w = (__bf16)(b.w * sc2);
    *(bf16x4*)(rep + (size_t)i * DIM + t * 4) = o1;
    *(bf16x4*)(rep + (size_t)(i + B_ROWS) * DIM + t * 4) = o2;
    if (t == 0) pos[i] = td * sc1 * sc2;
}

// Kernel 2: symmetric fused GEMM. Only upper-triangle tiles (rb <= cb).
// 128x128 tile, BK=32, 4 waves stacked vertically (32 rows each).
// LDS is fragment-contiguous: chunk g (16 rows x 32 k) stored as
// slot l = (seg<<4)|row16, so every ds_read_b128 is base + lane*16 (conflict-free).
// Row-partials  -> partial[cb*NN + grow]   (slot cb, rows of rb-block)
// Col-partials  -> partial[rb*NN + gcol]   (slot rb, rows of cb-block), rb<cb only.
// Row r in block i gets slots {i..63} from row-part, {0..i-1} from transpose: all 64, disjoint.
__global__ __launch_bounds__(256) void gemm_kernel(const __bf16* __restrict__ rep,
                                                   float* __restrict__ partial) {
    __shared__ __bf16 As[128 * 32];
    __shared__ __bf16 Bs[128 * 32];
    __shared__ float csum[4][128];
    const int t = threadIdx.x;
    const int lane = t & 63;
    const int wv = t >> 6;  // 0..3
    const int cm = lane & 15;   // row-in-group for staging / m,n index for frags
    const int q = lane >> 4;    // seg for staging / k-half group for frags

    // triangular decode: bid -> (rb, cb), rb <= cb, column-major triangle
    const int bid = blockIdx.x;
    int cb = (int)((sqrtf(8.0f * (float)bid + 1.0f) - 1.0f) * 0.5f);
    while ((cb + 1) * (cb + 2) / 2 <= bid) ++cb;
    while (cb * (cb + 1) / 2 > bid) --cb;
    const int rb = bid - cb * (cb + 1) / 2;

    // staging source: call1 group g=wv, call2 g=wv+4; row g*16+cm, 16B seg q
    const __bf16* aS = rep + (size_t)(rb * 128 + wv * 16 + cm) * DIM + q * 8;
    const __bf16* bS = rep + (size_t)(cb * 128 + wv * 16 + cm) * DIM + q * 8;
    __bf16* aD = As + t * 8;  // HW: wave-uniform base + lane*16
    __bf16* bD = Bs + t * 8;

    f32x4 acc[2][8];
#pragma unroll
    for (int i = 0; i < 2; ++i)
#pragma unroll
        for (int j = 0; j < 8; ++j) acc[i][j] = (f32x4){0.f, 0.f, 0.f, 0.f};

    for (int kk = 0; kk < DIM / 32; ++kk) {
        const __bf16* a0 = aS + kk * 32;
        const __bf16* b0 = bS + kk * 32;
        gld_lds16(a0, aD);
        gld_lds16(a0 + (size_t)64 * DIM, aD + 2048);
        gld_lds16(b0, bD);
        gld_lds16(b0 + (size_t)64 * DIM, bD + 2048);
        __syncthreads();

        bf16x8 af[2], bfr[8];
#pragma unroll
        for (int mi = 0; mi < 2; ++mi)
            af[mi] = *(const bf16x8*)(As + (wv * 2 + mi) * 512 + lane * 8);
#pragma unroll
        for (int ni = 0; ni < 8; ++ni)
            bfr[ni] = *(const bf16x8*)(Bs + ni * 512 + lane * 8);
#pragma unroll
        for (int mi = 0; mi < 2; ++mi)
#pragma unroll
            for (int ni = 0; ni < 8; ++ni)
                acc[mi][ni] = __builtin_amdgcn_mfma_f32_16x16x32_bf16(
                    af[mi], bfr[ni], acc[mi][ni], 0, 0, 0);
        __syncthreads();
    }

    // Epilogue. C/D layout: col = cm + ni*16, row = wv*32 + mi*16 + q*4 + reg.
    float colsum[8];
#pragma unroll
    for (int ni = 0; ni < 8; ++ni) colsum[ni] = 0.f;

#pragma unroll
    for (int mi = 0; mi < 2; ++mi) {
#pragma unroll
        for (int reg = 0; reg < 4; ++reg) {
            const int row_l = wv * 32 + mi * 16 + (q << 2) + reg;
            const int grow = rb * 128 + row_l;
            float rs = 0.f;
#pragma unroll
            for (int ni = 0; ni < 8; ++ni) {
                const int gcol = cb * 128 + ni * 16 + cm;
                const float e =
                    (grow == gcol) ? 0.f : __expf(acc[mi][ni][reg] * 2.0f);  // 1/T=2
                rs += e;
                colsum[ni] += e;
            }
            rs += __shfl_xor(rs, 1);
            rs += __shfl_xor(rs, 2);
            rs += __shfl_xor(rs, 4);
            rs += __shfl_xor(rs, 8);
            if (cm == 0) partial[(size_t)cb * NN + grow] = rs;
        }
    }

    if (rb != cb) {
        // colsum currently over this lane's 8 rows; fold over q groups -> wave's 32 rows
#pragma unroll
        for (int ni = 0; ni < 8; ++ni) {
            colsum[ni] += __shfl_xor(colsum[ni], 16);
            colsum[ni] += __shfl_xor(colsum[ni], 32);
        }
        if (q == 0) {
#pragma unroll
            for (int ni = 0; ni < 8; ++ni) csum[wv][ni * 16 + cm] = colsum[ni];
        }
        __syncthreads();
        if (t < 128) {
            const float c = csum[0][t] + csum[1][t] + csum[2][t] + csum[3][t];
            partial[(size_t)rb * NN + cb * 128 + t] = c;
        }
    }
}

// Kernel 3: per-row denom -> per-row loss -> 32 block sums
__global__ void reduce_rows_kernel(const float* __restrict__ partial,
                                   const float* __restrict__ pos,
                                   float* __restrict__ bsum) {
    const int r = blockIdx.x * 256 + threadIdx.x;  // 32 x 256 = 8192
    float s = 0.f;
    for (int kb = 0; kb < 64; ++kb) s += partial[(size_t)kb * NN + r];
    float v = __logf(s) - pos[r & (B_ROWS - 1)] * 2.0f;  // log(denom) - pos/T
    v = wave_reduce_sum(v);
    __shared__ float red[4];
    const int lane = threadIdx.x & 63, wv = threadIdx.x >> 6;
    if (lane == 0) red[wv] = v;
    __syncthreads();
    if (threadIdx.x == 0) bsum[blockIdx.x] = red[0] + red[1] + red[2] + red[3];
}

// Kernel 4: final scalar
__global__ void final_kernel(const float* __restrict__ bsum,
                             float* __restrict__ out) {
    float s = (threadIdx.x < 32) ? bsum[threadIdx.x] : 0.f;
    s = wave_reduce_sum(s);
    if (threadIdx.x == 0) out[0] = s * (1.0f / NN);
}

extern "C" void kernel_launch(void* const* d_in, const int* in_sizes, int n_in,
                              void* d_out, int out_size, void* d_ws, size_t ws_size,
                              hipStream_t stream) {
    const float* p1 = (const float*)d_in[0];
    const float* p2 = (const float*)d_in[1];
    char* ws = (char*)d_ws;
    __bf16* rep = (__bf16*)ws;                                     // 16 MiB
    float* partial = (float*)(ws + (size_t)16 * 1024 * 1024);      // 2 MiB (64 x 8192)
    float* pos = (float*)(ws + (size_t)18 * 1024 * 1024);          // 16 KiB
    float* bsum = (float*)(ws + (size_t)18 * 1024 * 1024 + 16384); // 128 B
    float* out = (float*)d_out;

    norm_pos_kernel<<<B_ROWS, 256, 0, stream>>>(p1, p2, rep, pos);
    gemm_kernel<<<2080, 256, 0, stream>>>(rep, partial);
    reduce_rows_kernel<<<32, 256, 0, stream>>>(partial, pos, bsum);
    final_kernel<<<1, 64, 0, stream>>>(bsum, out);
}

// Round 3
// 218.310 us; speedup vs baseline: 1.1179x; 1.0040x over previous
//
#include <hip/hip_runtime.h>
#include <hip/hip_bf16.h>
#include <cstdint>

#define B_ROWS 4096
#define DIM 1024
#define NN 8192  // 2*B

typedef __bf16 bf16x8 __attribute__((ext_vector_type(8)));
typedef __bf16 bf16x4 __attribute__((ext_vector_type(4)));
typedef float f32x4 __attribute__((ext_vector_type(4)));

__device__ __forceinline__ float wave_reduce_sum(float v) {
    v += __shfl_xor(v, 1);
    v += __shfl_xor(v, 2);
    v += __shfl_xor(v, 4);
    v += __shfl_xor(v, 8);
    v += __shfl_xor(v, 16);
    v += __shfl_xor(v, 32);
    return v;
}

__device__ __forceinline__ void gld_lds16(const void* g, void* l) {
    __builtin_amdgcn_global_load_lds(
        (__attribute__((address_space(1))) void*)(uintptr_t)g,
        (__attribute__((address_space(3))) void*)l, 16, 0, 0);
}

// Kernel 1: fused L2-normalize (both views) + fp32 positives.
__global__ void norm_pos_kernel(const float* __restrict__ p1,
                                const float* __restrict__ p2,
                                __bf16* __restrict__ rep,
                                float* __restrict__ pos) {
    const int i = blockIdx.x;   // 0..4095
    const int t = threadIdx.x;  // 0..255, one float4 each (DIM=1024)
    float4 a = ((const float4*)(p1 + (size_t)i * DIM))[t];
    float4 b = ((const float4*)(p2 + (size_t)i * DIM))[t];
    float s1 = a.x * a.x + a.y * a.y + a.z * a.z + a.w * a.w;
    float s2 = b.x * b.x + b.y * b.y + b.z * b.z + b.w * b.w;
    float dp = a.x * b.x + a.y * b.y + a.z * b.z + a.w * b.w;
    s1 = wave_reduce_sum(s1);
    s2 = wave_reduce_sum(s2);
    dp = wave_reduce_sum(dp);
    __shared__ float r1[4], r2[4], r3[4];
    const int lane = t & 63, wv = t >> 6;
    if (lane == 0) { r1[wv] = s1; r2[wv] = s2; r3[wv] = dp; }
    __syncthreads();
    const float t1 = r1[0] + r1[1] + r1[2] + r1[3];
    const float t2 = r2[0] + r2[1] + r2[2] + r2[3];
    const float td = r3[0] + r3[1] + r3[2] + r3[3];
    const float sc1 = rsqrtf(t1), sc2 = rsqrtf(t2);
    bf16x4 o1, o2;
    o1.x = (__bf16)(a.x * sc1); o1.y = (__bf16)(a.y * sc1);
    o1.z = (__bf16)(a.z * sc1); o1.w = (__bf16)(a.w * sc1);
    o2.x = (__bf16)(b.x * sc2); o2.y = (__bf16)(b.y * sc2);
    o2.z = (__bf16)(b.z * sc2); o2.w = (__bf16)(b.w * sc2);
    *(bf16x4*)(rep + (size_t)i * DIM + t * 4) = o1;
    *(bf16x4*)(rep + (size_t)(i + B_ROWS) * DIM + t * 4) = o2;
    if (t == 0) pos[i] = td * sc1 * sc2;
}

// Kernel 2: symmetric fused GEMM, upper-triangle tiles only (rb <= cb).
// ROW-MAJOR triangle ordering: consecutive bids share the A-tile (rb) and
// stream cb — concurrent blocks span ~8 A-tiles (1 MB, L2-resident), which
// is the dispatch-locality pattern R1's full 64x64 grid measured well on.
__global__ __launch_bounds__(256) void gemm_kernel(const __bf16* __restrict__ rep,
                                                   float* __restrict__ partial) {
    __shared__ __bf16 As[128 * 32];
    __shared__ __bf16 Bs[128 * 32];
    __shared__ float csum[4][128];
    const int t = threadIdx.x;
    const int lane = t & 63;
    const int wv = t >> 6;    // 0..3
    const int cm = lane & 15; // staging row-in-group / frag m,n index
    const int q = lane >> 4;  // staging 16B seg / frag k-half group

    // rb-major triangle decode: start(rb) = 64*rb - rb*(rb-1)/2
    const int bid = blockIdx.x;
    int rb = (int)(64.5f - sqrtf(4160.25f - 2.0f * (float)bid));
    while (64 * (rb + 1) - (rb + 1) * rb / 2 <= bid) ++rb;
    while (64 * rb - rb * (rb - 1) / 2 > bid) --rb;
    const int cb = rb + (bid - (64 * rb - rb * (rb - 1) / 2));

    // staging: call1 group g=wv, call2 g=wv+4; row g*16+cm, 16B seg q.
    // LDS fragment-contiguous: every ds_read_b128 is base + lane*16 (conflict-free).
    const __bf16* aS = rep + (size_t)(rb * 128 + wv * 16 + cm) * DIM + q * 8;
    const __bf16* bS = rep + (size_t)(cb * 128 + wv * 16 + cm) * DIM + q * 8;
    __bf16* aD = As + t * 8;
    __bf16* bD = Bs + t * 8;

    f32x4 acc[2][8];
#pragma unroll
    for (int i = 0; i < 2; ++i)
#pragma unroll
        for (int j = 0; j < 8; ++j) acc[i][j] = (f32x4){0.f, 0.f, 0.f, 0.f};

    for (int kk = 0; kk < DIM / 32; ++kk) {
        const __bf16* a0 = aS + kk * 32;
        const __bf16* b0 = bS + kk * 32;
        gld_lds16(a0, aD);
        gld_lds16(a0 + (size_t)64 * DIM, aD + 2048);
        gld_lds16(b0, bD);
        gld_lds16(b0 + (size_t)64 * DIM, bD + 2048);
        __syncthreads();

        bf16x8 af[2], bfr[8];
#pragma unroll
        for (int mi = 0; mi < 2; ++mi)
            af[mi] = *(const bf16x8*)(As + (wv * 2 + mi) * 512 + lane * 8);
#pragma unroll
        for (int ni = 0; ni < 8; ++ni)
            bfr[ni] = *(const bf16x8*)(Bs + ni * 512 + lane * 8);
#pragma unroll
        for (int mi = 0; mi < 2; ++mi)
#pragma unroll
            for (int ni = 0; ni < 8; ++ni)
                acc[mi][ni] = __builtin_amdgcn_mfma_f32_16x16x32_bf16(
                    af[mi], bfr[ni], acc[mi][ni], 0, 0, 0);
        __syncthreads();
    }

    // Epilogue. C/D layout: col = cm + ni*16, row = wv*32 + mi*16 + q*4 + reg.
    // Row-partials -> partial[cb*NN + grow]; transpose col-partials -> partial[rb*NN + gcol].
    // Row r of block i receives slots {i..63} (row side) and {0..i-1} (transpose): disjoint.
    float colsum[8];
#pragma unroll
    for (int ni = 0; ni < 8; ++ni) colsum[ni] = 0.f;

#pragma unroll
    for (int mi = 0; mi < 2; ++mi) {
#pragma unroll
        for (int reg = 0; reg < 4; ++reg) {
            const int row_l = wv * 32 + mi * 16 + (q << 2) + reg;
            const int grow = rb * 128 + row_l;
            float rs = 0.f;
#pragma unroll
            for (int ni = 0; ni < 8; ++ni) {
                const int gcol = cb * 128 + ni * 16 + cm;
                const float e =
                    (grow == gcol) ? 0.f : __expf(acc[mi][ni][reg] * 2.0f);  // 1/T=2
                rs += e;
                colsum[ni] += e;
            }
            rs += __shfl_xor(rs, 1);
            rs += __shfl_xor(rs, 2);
            rs += __shfl_xor(rs, 4);
            rs += __shfl_xor(rs, 8);
            if (cm == 0) partial[(size_t)cb * NN + grow] = rs;
        }
    }

    if (rb != cb) {
#pragma unroll
        for (int ni = 0; ni < 8; ++ni) {
            colsum[ni] += __shfl_xor(colsum[ni], 16);
            colsum[ni] += __shfl_xor(colsum[ni], 32);
        }
        if (q == 0) {
#pragma unroll
            for (int ni = 0; ni < 8; ++ni) csum[wv][ni * 16 + cm] = colsum[ni];
        }
        __syncthreads();
        if (t < 128) {
            const float c = csum[0][t] + csum[1][t] + csum[2][t] + csum[3][t];
            partial[(size_t)rb * NN + cb * 128 + t] = c;
        }
    }
}

// Kernel 3: per-row denom -> per-row loss -> atomic accumulate into out[0]
// (out[0] zeroed by hipMemsetAsync before this kernel).
__global__ void reduce_rows_kernel(const float* __restrict__ partial,
                                   const float* __restrict__ pos,
                                   float* __restrict__ out) {
    const int r = blockIdx.x * 256 + threadIdx.x;  // 32 x 256 = 8192
    float s = 0.f;
    for (int kb = 0; kb < 64; ++kb) s += partial[(size_t)kb * NN + r];
    float v = __logf(s) - pos[r & (B_ROWS - 1)] * 2.0f;  // log(denom) - pos/T
    v = wave_reduce_sum(v);
    __shared__ float red[4];
    const int lane = threadIdx.x & 63, wv = threadIdx.x >> 6;
    if (lane == 0) red[wv] = v;
    __syncthreads();
    if (threadIdx.x == 0)
        atomicAdd(out, (red[0] + red[1] + red[2] + red[3]) * (1.0f / NN));
}

extern "C" void kernel_launch(void* const* d_in, const int* in_sizes, int n_in,
                              void* d_out, int out_size, void* d_ws, size_t ws_size,
                              hipStream_t stream) {
    const float* p1 = (const float*)d_in[0];
    const float* p2 = (const float*)d_in[1];
    char* ws = (char*)d_ws;
    __bf16* rep = (__bf16*)ws;                                 // 16 MiB
    float* partial = (float*)(ws + (size_t)16 * 1024 * 1024);  // 2 MiB (64 x 8192)
    float* pos = (float*)(ws + (size_t)18 * 1024 * 1024);      // 16 KiB
    float* out = (float*)d_out;

    hipMemsetAsync(out, 0, sizeof(float), stream);
    norm_pos_kernel<<<B_ROWS, 256, 0, stream>>>(p1, p2, rep, pos);
    gemm_kernel<<<2080, 256, 0, stream>>>(rep, partial);
    reduce_rows_kernel<<<32, 256, 0, stream>>>(partial, pos, out);
}